// Round 1
// baseline (3372.182 us; speedup 1.0000x reference)
//
#include <hip/hip_runtime.h>

#define NG 4096       // graphs
#define NN 524288     // nodes
#define H  128        // hidden
#define H2 256        // 2*H

// ---------------------------------------------------------------------------
// Kernel 1: segment sum. One block per graph; segment_ids is sorted, so find
// [start,end) by binary search. 128 threads = one per feature column.
// ---------------------------------------------------------------------------
__global__ __launch_bounds__(128) void seg_sum_kernel(
    const float* __restrict__ node, const int* __restrict__ seg,
    float* __restrict__ agg) {
    const int g = blockIdx.x;
    const int h = threadIdx.x;

    // lower_bound(seg, g)
    int lo = 0, hi = NN;
    while (lo < hi) { int mid = (lo + hi) >> 1; if (seg[mid] < g) lo = mid + 1; else hi = mid; }
    const int start = lo;
    // lower_bound(seg, g+1)
    hi = NN;
    while (lo < hi) { int mid = (lo + hi) >> 1; if (seg[mid] < g + 1) lo = mid + 1; else hi = mid; }
    const int end = lo;

    float acc = 0.f;
    for (int i = start; i < end; ++i)
        acc += node[(size_t)i * H + h];
    agg[(size_t)g * H + h] = acc;
}

// ---------------------------------------------------------------------------
// Kernel 2: set MLP.  s = relu(relu([agg, set] @ Ws1 + bs1) @ Ws2 + bs2)
// One block (128 threads) per graph row. Weights come from L2 (192 KB total).
// ---------------------------------------------------------------------------
__global__ __launch_bounds__(128) void set_mlp_kernel(
    const float* __restrict__ agg, const float* __restrict__ uset,
    const float* __restrict__ Ws1, const float* __restrict__ bs1,
    const float* __restrict__ Ws2, const float* __restrict__ bs2,
    float* __restrict__ s_out) {
    __shared__ float sin[H2];
    __shared__ float h1[H];
    const int g = blockIdx.x;
    const int j = threadIdx.x;

    sin[j]     = agg[(size_t)g * H + j];
    sin[j + H] = uset[(size_t)g * H + j];
    __syncthreads();

    float acc = bs1[j];
    #pragma unroll 8
    for (int k = 0; k < H2; ++k)
        acc = fmaf(sin[k], Ws1[k * H + j], acc);
    h1[j] = fmaxf(acc, 0.f);
    __syncthreads();

    acc = bs2[j];
    #pragma unroll 8
    for (int k = 0; k < H; ++k)
        acc = fmaf(h1[k], Ws2[k * H + j], acc);
    s_out[(size_t)g * H + j] = fmaxf(acc, 0.f);
}

// ---------------------------------------------------------------------------
// Kernel 3: node MLP.  n = relu(relu([node, s[seg]] @ Wn1 + bn1) @ Wn2 + bn2)
// 256 threads process 2 nodes at a time (thread t: node = t>>7, j = t&127).
// Inputs staged in LDS; weights streamed from L1/L2 (coalesced 256 B/wave).
// ---------------------------------------------------------------------------
#define NODES_PER_BLOCK 32
__global__ __launch_bounds__(256) void node_mlp_kernel(
    const float* __restrict__ node, const int* __restrict__ seg,
    const float* __restrict__ s,
    const float* __restrict__ Wn1, const float* __restrict__ bn1,
    const float* __restrict__ Wn2, const float* __restrict__ bn2,
    float* __restrict__ n_out) {
    __shared__ float nin[2][H2];
    __shared__ float h1[2][H];

    const int base  = blockIdx.x * NODES_PER_BLOCK;
    const int t     = threadIdx.x;
    const int which = t >> 7;        // 0 or 1: which node of the pair
    const int j     = t & (H - 1);   // output feature

    for (int p = 0; p < NODES_PER_BLOCK; p += 2) {
        const int n_i = base + p + which;
        const int sg  = seg[n_i];                     // uniform per half-block
        nin[which][j]     = node[(size_t)n_i * H + j];
        nin[which][H + j] = s[(size_t)sg * H + j];
        __syncthreads();

        float acc = bn1[j];
        #pragma unroll 8
        for (int k = 0; k < H2; ++k)
            acc = fmaf(nin[which][k], Wn1[k * H + j], acc);
        h1[which][j] = fmaxf(acc, 0.f);
        __syncthreads();

        acc = bn2[j];
        #pragma unroll 8
        for (int k = 0; k < H; ++k)
            acc = fmaf(h1[which][k], Wn2[k * H + j], acc);
        n_out[(size_t)n_i * H + j] = fmaxf(acc, 0.f);
        // No third barrier needed: next-iter nin writes are ordered against
        // this iter's nin reads by the mid barrier, and h1 reads touch a
        // different array than the next nin write.
    }
}

extern "C" void kernel_launch(void* const* d_in, const int* in_sizes, int n_in,
                              void* d_out, int out_size, void* d_ws, size_t ws_size,
                              hipStream_t stream) {
    const float* updated_set  = (const float*)d_in[0];   // [G,H]
    const float* updated_node = (const float*)d_in[1];   // [N,H]
    const int*   segment_ids  = (const int*)  d_in[2];   // [N]
    const float* Ws1 = (const float*)d_in[3];            // [2H,H]
    const float* bs1 = (const float*)d_in[4];            // [H]
    const float* Ws2 = (const float*)d_in[5];            // [H,H]
    const float* bs2 = (const float*)d_in[6];            // [H]
    const float* Wn1 = (const float*)d_in[7];            // [2H,H]
    const float* bn1 = (const float*)d_in[8];            // [H]
    const float* Wn2 = (const float*)d_in[9];            // [H,H]
    const float* bn2 = (const float*)d_in[10];           // [H]

    float* s_out = (float*)d_out;                        // [G,H] at offset 0
    float* n_out = (float*)d_out + (size_t)NG * H;       // [N,H] after s
    float* agg   = (float*)d_ws;                         // [G,H] scratch (2 MB)

    seg_sum_kernel<<<NG, 128, 0, stream>>>(updated_node, segment_ids, agg);
    set_mlp_kernel<<<NG, 128, 0, stream>>>(agg, updated_set, Ws1, bs1, Ws2, bs2, s_out);
    node_mlp_kernel<<<NN / NODES_PER_BLOCK, 256, 0, stream>>>(
        updated_node, segment_ids, s_out, Wn1, bn1, Wn2, bn2, n_out);
}

// Round 2
// 763.508 us; speedup vs baseline: 4.4167x; 4.4167x over previous
//
#include <hip/hip_runtime.h>

#define NG 4096       // graphs
#define NN 524288     // nodes
#define H  128        // hidden
#define H2 256        // 2*H

typedef __attribute__((ext_vector_type(8))) short bf16x8;
typedef __attribute__((ext_vector_type(4))) float floatx4;
typedef __attribute__((ext_vector_type(2))) unsigned int uint2v;

__device__ __forceinline__ unsigned short bf16r(float f) {
    unsigned int u = __builtin_bit_cast(unsigned int, f);
    u += 0x7fffu + ((u >> 16) & 1u);          // RNE truncate to bf16
    return (unsigned short)(u >> 16);
}
__device__ __forceinline__ unsigned int bf16pk2(float a, float b) {
    return (unsigned int)bf16r(a) | ((unsigned int)bf16r(b) << 16);
}
__device__ __forceinline__ bf16x8 pack8(floatx4 a, floatx4 b) {
    union { unsigned int u[4]; bf16x8 v; } r;
    r.u[0] = bf16pk2(a[0], a[1]);
    r.u[1] = bf16pk2(a[2], a[3]);
    r.u[2] = bf16pk2(b[0], b[1]);
    r.u[3] = bf16pk2(b[2], b[3]);
    return r.v;
}

// ---------------------------------------------------------------------------
// Kernel 1: segment sum (sorted ids -> binary search bounds). 128 threads =
// one lane per feature column; unroll-4 over rows for load ILP.
// ---------------------------------------------------------------------------
__global__ __launch_bounds__(128) void seg_sum_kernel(
    const float* __restrict__ node, const int* __restrict__ seg,
    float* __restrict__ agg) {
    const int g = blockIdx.x;
    const int h = threadIdx.x;

    int lo = 0, hi = NN;
    while (lo < hi) { int mid = (lo + hi) >> 1; if (seg[mid] < g) lo = mid + 1; else hi = mid; }
    const int start = lo;
    hi = NN;
    while (lo < hi) { int mid = (lo + hi) >> 1; if (seg[mid] < g + 1) lo = mid + 1; else hi = mid; }
    const int end = lo;

    float a0 = 0.f, a1 = 0.f, a2 = 0.f, a3 = 0.f;
    int i = start;
    for (; i + 3 < end; i += 4) {
        a0 += node[(size_t)i * H + h];
        a1 += node[(size_t)(i + 1) * H + h];
        a2 += node[(size_t)(i + 2) * H + h];
        a3 += node[(size_t)(i + 3) * H + h];
    }
    for (; i < end; ++i) a0 += node[(size_t)i * H + h];
    agg[(size_t)g * H + h] = (a0 + a1) + (a2 + a3);
}

// ---------------------------------------------------------------------------
// Kernel 2: set MLP (fp32 exact; small: 0.4 GFLOP total).
// ---------------------------------------------------------------------------
__global__ __launch_bounds__(128) void set_mlp_kernel(
    const float* __restrict__ agg, const float* __restrict__ uset,
    const float* __restrict__ Ws1, const float* __restrict__ bs1,
    const float* __restrict__ Ws2, const float* __restrict__ bs2,
    float* __restrict__ s_out) {
    __shared__ float sin[H2];
    __shared__ float h1[H];
    const int g = blockIdx.x;
    const int j = threadIdx.x;

    sin[j]     = agg[(size_t)g * H + j];
    sin[j + H] = uset[(size_t)g * H + j];
    __syncthreads();

    float acc = bs1[j];
    #pragma unroll 8
    for (int k = 0; k < H2; ++k)
        acc = fmaf(sin[k], Ws1[k * H + j], acc);
    h1[j] = fmaxf(acc, 0.f);
    __syncthreads();

    acc = bs2[j];
    #pragma unroll 8
    for (int k = 0; k < H; ++k)
        acc = fmaf(h1[k], Ws2[k * H + j], acc);
    s_out[(size_t)g * H + j] = fmaxf(acc, 0.f);
}

// ---------------------------------------------------------------------------
// Kernel 3: node MLP via bf16 MFMA, weight-stationary.
//   out^T = relu(Wn2^T @ relu(Wn1^T @ in^T + bn1) + bn2)
// Block = 256 threads = 4 waves; wave w owns output features [32w, 32w+32).
// A-fragments (weights, transposed) live in VGPRs for the whole kernel.
// B-fragments (node rows) load straight from global: lane reads 8 consecutive
// k of node (lane&15) -> two dwordx4 + bf16 pack. h1 and out round-trip
// through LDS (padded strides 136/132 -> 2-way bank aliasing, free).
// ---------------------------------------------------------------------------
#define TILES 8   // 16-node tiles per block -> 128 nodes/block

__global__ __launch_bounds__(256, 2) void node_mlp_mfma(
    const float* __restrict__ node, const int* __restrict__ seg,
    const float* __restrict__ s,
    const float* __restrict__ Wn1, const float* __restrict__ bn1,
    const float* __restrict__ Wn2, const float* __restrict__ bn2,
    float* __restrict__ n_out) {

    __shared__ unsigned short h1s[16 * 136];  // [node][feat], bf16, pad->136
    __shared__ float outs[16 * 132];          // [node][feat], f32, pad->132

    const int tid   = threadIdx.x;
    const int wid   = tid >> 6;
    const int lane  = tid & 63;
    const int l16   = lane & 15;
    const int quad  = lane >> 4;
    const int fbase = wid * 32;               // wave's first output feature

    // ---- stationary weight fragments: A[m=lane&15][k=quad*8+j] = W[k][m] ----
    bf16x8 A1[2][8];
    #pragma unroll
    for (int mt = 0; mt < 2; ++mt)
        #pragma unroll
        for (int kt = 0; kt < 8; ++kt) {
            const float* b = Wn1 + (size_t)(kt * 32 + quad * 8) * H
                                 + fbase + mt * 16 + l16;
            union { unsigned int u[4]; bf16x8 v; } r;
            #pragma unroll
            for (int j = 0; j < 4; ++j)
                r.u[j] = bf16pk2(b[(2 * j) * H], b[(2 * j + 1) * H]);
            A1[mt][kt] = r.v;
        }
    bf16x8 A2[2][4];
    #pragma unroll
    for (int mt = 0; mt < 2; ++mt)
        #pragma unroll
        for (int kt = 0; kt < 4; ++kt) {
            const float* b = Wn2 + (size_t)(kt * 32 + quad * 8) * H
                                 + fbase + mt * 16 + l16;
            union { unsigned int u[4]; bf16x8 v; } r;
            #pragma unroll
            for (int j = 0; j < 4; ++j)
                r.u[j] = bf16pk2(b[(2 * j) * H], b[(2 * j + 1) * H]);
            A2[mt][kt] = r.v;
        }
    floatx4 b1v[2], b2v[2];
    #pragma unroll
    for (int mt = 0; mt < 2; ++mt) {
        b1v[mt] = *(const floatx4*)(bn1 + fbase + mt * 16 + quad * 4);
        b2v[mt] = *(const floatx4*)(bn2 + fbase + mt * 16 + quad * 4);
    }

    const int nb0 = blockIdx.x * (TILES * 16);
    for (int t = 0; t < TILES; ++t) {
        const int nb  = nb0 + t * 16;
        const int row = nb + l16;
        const int sg  = seg[row];
        const float* nrow = node + (size_t)row * H;
        const float* srow = s    + (size_t)sg  * H;

        // ---- GEMM1: C1^T[feat][node], K = 256 ----
        floatx4 acc1[2];
        acc1[0] = (floatx4){0.f, 0.f, 0.f, 0.f};
        acc1[1] = (floatx4){0.f, 0.f, 0.f, 0.f};
        #pragma unroll
        for (int kt = 0; kt < 8; ++kt) {
            const float* src = (kt < 4) ? (nrow + kt * 32 + quad * 8)
                                        : (srow + (kt - 4) * 32 + quad * 8);
            floatx4 f0 = *(const floatx4*)src;
            floatx4 f1 = *(const floatx4*)(src + 4);
            bf16x8 bf = pack8(f0, f1);
            acc1[0] = __builtin_amdgcn_mfma_f32_16x16x32_bf16(A1[0][kt], bf, acc1[0], 0, 0, 0);
            acc1[1] = __builtin_amdgcn_mfma_f32_16x16x32_bf16(A1[1][kt], bf, acc1[1], 0, 0, 0);
        }
        // bias + relu + bf16, write h1s[node][feat] (4 consecutive feats/lane)
        #pragma unroll
        for (int mt = 0; mt < 2; ++mt) {
            floatx4 v = acc1[mt] + b1v[mt];
            uint2v u;
            u[0] = bf16pk2(fmaxf(v[0], 0.f), fmaxf(v[1], 0.f));
            u[1] = bf16pk2(fmaxf(v[2], 0.f), fmaxf(v[3], 0.f));
            *(uint2v*)&h1s[l16 * 136 + fbase + mt * 16 + quad * 4] = u;
        }
        __syncthreads();

        // ---- GEMM2: out^T = Wn2^T @ h1^T, K = 128 ----
        floatx4 acc2[2];
        acc2[0] = (floatx4){0.f, 0.f, 0.f, 0.f};
        acc2[1] = (floatx4){0.f, 0.f, 0.f, 0.f};
        #pragma unroll
        for (int kt = 0; kt < 4; ++kt) {
            bf16x8 bf = *(const bf16x8*)&h1s[l16 * 136 + kt * 32 + quad * 8];
            acc2[0] = __builtin_amdgcn_mfma_f32_16x16x32_bf16(A2[0][kt], bf, acc2[0], 0, 0, 0);
            acc2[1] = __builtin_amdgcn_mfma_f32_16x16x32_bf16(A2[1][kt], bf, acc2[1], 0, 0, 0);
        }
        #pragma unroll
        for (int mt = 0; mt < 2; ++mt) {
            floatx4 v = acc2[mt] + b2v[mt];
            floatx4 o;
            o[0] = fmaxf(v[0], 0.f); o[1] = fmaxf(v[1], 0.f);
            o[2] = fmaxf(v[2], 0.f); o[3] = fmaxf(v[3], 0.f);
            *(floatx4*)&outs[l16 * 132 + fbase + mt * 16 + quad * 4] = o;
        }
        __syncthreads();

        // ---- coalesced writeback: block writes 16 rows x 512 B contiguous ----
        {
            const int nidx = tid >> 4;
            const int col  = (tid & 15) * 8;
            floatx4 o0 = *(const floatx4*)&outs[nidx * 132 + col];
            floatx4 o1 = *(const floatx4*)&outs[nidx * 132 + col + 4];
            float* dst = n_out + (size_t)(nb + nidx) * H + col;
            *(floatx4*)dst       = o0;
            *(floatx4*)(dst + 4) = o1;
        }
        __syncthreads();
    }
}

extern "C" void kernel_launch(void* const* d_in, const int* in_sizes, int n_in,
                              void* d_out, int out_size, void* d_ws, size_t ws_size,
                              hipStream_t stream) {
    const float* updated_set  = (const float*)d_in[0];   // [G,H]
    const float* updated_node = (const float*)d_in[1];   // [N,H]
    const int*   segment_ids  = (const int*)  d_in[2];   // [N]
    const float* Ws1 = (const float*)d_in[3];            // [2H,H]
    const float* bs1 = (const float*)d_in[4];            // [H]
    const float* Ws2 = (const float*)d_in[5];            // [H,H]
    const float* bs2 = (const float*)d_in[6];            // [H]
    const float* Wn1 = (const float*)d_in[7];            // [2H,H]
    const float* bn1 = (const float*)d_in[8];            // [H]
    const float* Wn2 = (const float*)d_in[9];            // [H,H]
    const float* bn2 = (const float*)d_in[10];           // [H]

    float* s_out = (float*)d_out;                        // [G,H]
    float* n_out = (float*)d_out + (size_t)NG * H;       // [N,H]
    float* agg   = (float*)d_ws;                         // [G,H] scratch

    seg_sum_kernel<<<NG, 128, 0, stream>>>(updated_node, segment_ids, agg);
    set_mlp_kernel<<<NG, 128, 0, stream>>>(agg, updated_set, Ws1, bs1, Ws2, bs2, s_out);
    node_mlp_mfma<<<NN / (TILES * 16), 256, 0, stream>>>(
        updated_node, segment_ids, s_out, Wn1, bn1, Wn2, bn2, n_out);
}

// Round 3
// 686.050 us; speedup vs baseline: 4.9154x; 1.1129x over previous
//
#include <hip/hip_runtime.h>

#define NG 4096       // graphs
#define NN 524288     // nodes
#define H  128        // hidden
#define H2 256        // 2*H

typedef __attribute__((ext_vector_type(8))) short bf16x8;
typedef __attribute__((ext_vector_type(4))) float floatx4;
typedef __attribute__((ext_vector_type(2))) unsigned int uint2v;

__device__ __forceinline__ unsigned short bf16r(float f) {
    unsigned int u = __builtin_bit_cast(unsigned int, f);
    u += 0x7fffu + ((u >> 16) & 1u);          // RNE truncate to bf16
    return (unsigned short)(u >> 16);
}
__device__ __forceinline__ unsigned int bf16pk2(float a, float b) {
    return (unsigned int)bf16r(a) | ((unsigned int)bf16r(b) << 16);
}
__device__ __forceinline__ bf16x8 pack8(floatx4 a, floatx4 b) {
    union { unsigned int u[4]; bf16x8 v; } r;
    r.u[0] = bf16pk2(a[0], a[1]);
    r.u[1] = bf16pk2(a[2], a[3]);
    r.u[2] = bf16pk2(b[0], b[1]);
    r.u[3] = bf16pk2(b[2], b[3]);
    return r.v;
}

// ---------------------------------------------------------------------------
// Kernel 1: segment sum, streaming + atomics. Block owns 256 contiguous rows
// split into 4 independent run-chains (ILP-4, coalesced 256 B wave loads).
// Sorted segment_ids -> run boundaries are rare & wave-uniform; atomicAdd only
// at boundaries (~6 flushes x 128 floats per block). agg must be pre-zeroed.
// ---------------------------------------------------------------------------
#define SS_ROWS 256
#define SS_SUB  4
#define SS_LEN  (SS_ROWS / SS_SUB)   // 64

__global__ __launch_bounds__(128) void seg_sum_atomic(
    const float* __restrict__ node, const int* __restrict__ seg,
    float* __restrict__ agg) {
    const int j    = threadIdx.x;
    const int base = blockIdx.x * SS_ROWS;

    float acc[SS_SUB];
    int   cur[SS_SUB];
    #pragma unroll
    for (int c = 0; c < SS_SUB; ++c) {
        cur[c] = seg[base + c * SS_LEN];
        acc[c] = 0.f;
    }
    for (int r = 0; r < SS_LEN; ++r) {
        #pragma unroll
        for (int c = 0; c < SS_SUB; ++c) {
            const int   row = base + c * SS_LEN + r;
            const int   sgv = seg[row];
            const float v   = node[(size_t)row * H + j];
            if (sgv != cur[c]) {                       // wave-uniform branch
                atomicAdd(&agg[(size_t)cur[c] * H + j], acc[c]);
                acc[c] = 0.f;
                cur[c] = sgv;
            }
            acc[c] += v;
        }
    }
    #pragma unroll
    for (int c = 0; c < SS_SUB; ++c)
        atomicAdd(&agg[(size_t)cur[c] * H + j], acc[c]);
}

// ---------------------------------------------------------------------------
// Kernel 2+3: fused 2-layer MLP via bf16 MFMA, weight-stationary.
//   out = relu(relu([in0[row], in1[gather(row)]] @ W1 + b1) @ W2 + b2)
// Block = 256 thr = 4 waves; wave w owns output feats [32w,32w+32).
// A-frags (W^T) stationary in VGPRs. B-frags (rows) straight from global.
// Double-buffered h1 LDS -> ONE barrier per 16-row tile. Next tile's in0 row
// prefetched into VGPRs before the barrier. Direct C-layout global stores
// (16 rows x 64 B per instr), nontemporal when NT (streaming 268 MB output).
// ---------------------------------------------------------------------------
template<int TILES_, bool GATHER, bool NT>
__global__ __launch_bounds__(256) void mlp_mfma(
    const float* __restrict__ in0, const int* __restrict__ seg,
    const float* __restrict__ in1,
    const float* __restrict__ W1, const float* __restrict__ b1,
    const float* __restrict__ W2, const float* __restrict__ b2,
    float* __restrict__ outp) {

    __shared__ unsigned short h1s[2][16 * 136];  // [buf][row][feat] bf16, pad->136

    const int tid   = threadIdx.x;
    const int wid   = tid >> 6;
    const int lane  = tid & 63;
    const int l16   = lane & 15;
    const int quad  = lane >> 4;
    const int fbase = wid * 32;

    // ---- stationary weights: A[m=lane&15][k=quad*8+j] = W[k][m] ----
    bf16x8 A1[2][8];
    #pragma unroll
    for (int mt = 0; mt < 2; ++mt)
        #pragma unroll
        for (int kt = 0; kt < 8; ++kt) {
            const float* b = W1 + (size_t)(kt * 32 + quad * 8) * H
                                + fbase + mt * 16 + l16;
            union { unsigned int u[4]; bf16x8 v; } r;
            #pragma unroll
            for (int j = 0; j < 4; ++j)
                r.u[j] = bf16pk2(b[(2 * j) * H], b[(2 * j + 1) * H]);
            A1[mt][kt] = r.v;
        }
    bf16x8 A2[2][4];
    #pragma unroll
    for (int mt = 0; mt < 2; ++mt)
        #pragma unroll
        for (int kt = 0; kt < 4; ++kt) {
            const float* b = W2 + (size_t)(kt * 32 + quad * 8) * H
                                + fbase + mt * 16 + l16;
            union { unsigned int u[4]; bf16x8 v; } r;
            #pragma unroll
            for (int j = 0; j < 4; ++j)
                r.u[j] = bf16pk2(b[(2 * j) * H], b[(2 * j + 1) * H]);
            A2[mt][kt] = r.v;
        }
    floatx4 b1v[2], b2v[2];
    #pragma unroll
    for (int mt = 0; mt < 2; ++mt) {
        b1v[mt] = *(const floatx4*)(b1 + fbase + mt * 16 + quad * 4);
        b2v[mt] = *(const floatx4*)(b2 + fbase + mt * 16 + quad * 4);
    }

    const int nb0 = blockIdx.x * (TILES_ * 16);

    // ---- prologue: prefetch tile 0's in0 row + gather id ----
    int sg;
    floatx4 pf[8];
    {
        const int row = nb0 + l16;
        sg = GATHER ? seg[row] : row;
        const float* p = in0 + (size_t)row * H;
        #pragma unroll
        for (int i = 0; i < 4; ++i) {
            pf[2 * i]     = *(const floatx4*)(p + i * 32 + quad * 8);
            pf[2 * i + 1] = *(const floatx4*)(p + i * 32 + quad * 8 + 4);
        }
    }

    for (int t = 0; t < TILES_; ++t) {
        const int nb = nb0 + t * 16;
        const float* srow = in1 + (size_t)sg * H;

        // ---- GEMM1: K=256 (first 128 from prefetch regs, rest from in1) ----
        floatx4 acc1[2];
        acc1[0] = (floatx4){0.f, 0.f, 0.f, 0.f};
        acc1[1] = (floatx4){0.f, 0.f, 0.f, 0.f};
        #pragma unroll
        for (int kt = 0; kt < 4; ++kt) {
            bf16x8 bf = pack8(pf[2 * kt], pf[2 * kt + 1]);
            acc1[0] = __builtin_amdgcn_mfma_f32_16x16x32_bf16(A1[0][kt], bf, acc1[0], 0, 0, 0);
            acc1[1] = __builtin_amdgcn_mfma_f32_16x16x32_bf16(A1[1][kt], bf, acc1[1], 0, 0, 0);
        }
        #pragma unroll
        for (int kt = 4; kt < 8; ++kt) {
            floatx4 f0 = *(const floatx4*)(srow + (kt - 4) * 32 + quad * 8);
            floatx4 f1 = *(const floatx4*)(srow + (kt - 4) * 32 + quad * 8 + 4);
            bf16x8 bf = pack8(f0, f1);
            acc1[0] = __builtin_amdgcn_mfma_f32_16x16x32_bf16(A1[0][kt], bf, acc1[0], 0, 0, 0);
            acc1[1] = __builtin_amdgcn_mfma_f32_16x16x32_bf16(A1[1][kt], bf, acc1[1], 0, 0, 0);
        }
        // bias + relu + pack -> h1s[t&1]
        #pragma unroll
        for (int mt = 0; mt < 2; ++mt) {
            floatx4 v = acc1[mt] + b1v[mt];
            uint2v u;
            u[0] = bf16pk2(fmaxf(v[0], 0.f), fmaxf(v[1], 0.f));
            u[1] = bf16pk2(fmaxf(v[2], 0.f), fmaxf(v[3], 0.f));
            *(uint2v*)&h1s[t & 1][l16 * 136 + fbase + mt * 16 + quad * 4] = u;
        }

        // ---- prefetch tile t+1 BEFORE the barrier (loads fly across it) ----
        if (t + 1 < TILES_) {
            const int row = nb + 16 + l16;
            sg = GATHER ? seg[row] : row;
            const float* p = in0 + (size_t)row * H;
            #pragma unroll
            for (int i = 0; i < 4; ++i) {
                pf[2 * i]     = *(const floatx4*)(p + i * 32 + quad * 8);
                pf[2 * i + 1] = *(const floatx4*)(p + i * 32 + quad * 8 + 4);
            }
        }

        __syncthreads();   // h1s[t&1] writes visible; dbuf makes this the ONLY barrier

        // ---- GEMM2: K=128 from LDS ----
        floatx4 acc2[2];
        acc2[0] = (floatx4){0.f, 0.f, 0.f, 0.f};
        acc2[1] = (floatx4){0.f, 0.f, 0.f, 0.f};
        #pragma unroll
        for (int kt = 0; kt < 4; ++kt) {
            bf16x8 bf = *(const bf16x8*)&h1s[t & 1][l16 * 136 + kt * 32 + quad * 8];
            acc2[0] = __builtin_amdgcn_mfma_f32_16x16x32_bf16(A2[0][kt], bf, acc2[0], 0, 0, 0);
            acc2[1] = __builtin_amdgcn_mfma_f32_16x16x32_bf16(A2[1][kt], bf, acc2[1], 0, 0, 0);
        }
        // ---- bias + relu + direct C-layout store (16 B/lane, 64 B/row/instr) ----
        #pragma unroll
        for (int mt = 0; mt < 2; ++mt) {
            floatx4 v = acc2[mt] + b2v[mt];
            floatx4 o;
            o[0] = fmaxf(v[0], 0.f); o[1] = fmaxf(v[1], 0.f);
            o[2] = fmaxf(v[2], 0.f); o[3] = fmaxf(v[3], 0.f);
            float* dst = outp + (size_t)(nb + l16) * H + fbase + mt * 16 + quad * 4;
            if (NT) __builtin_nontemporal_store(o, (floatx4*)dst);
            else    *(floatx4*)dst = o;
        }
    }
}

extern "C" void kernel_launch(void* const* d_in, const int* in_sizes, int n_in,
                              void* d_out, int out_size, void* d_ws, size_t ws_size,
                              hipStream_t stream) {
    const float* updated_set  = (const float*)d_in[0];   // [G,H]
    const float* updated_node = (const float*)d_in[1];   // [N,H]
    const int*   segment_ids  = (const int*)  d_in[2];   // [N]
    const float* Ws1 = (const float*)d_in[3];            // [2H,H]
    const float* bs1 = (const float*)d_in[4];            // [H]
    const float* Ws2 = (const float*)d_in[5];            // [H,H]
    const float* bs2 = (const float*)d_in[6];            // [H]
    const float* Wn1 = (const float*)d_in[7];            // [2H,H]
    const float* bn1 = (const float*)d_in[8];            // [H]
    const float* Wn2 = (const float*)d_in[9];            // [H,H]
    const float* bn2 = (const float*)d_in[10];           // [H]

    float* s_out = (float*)d_out;                        // [G,H]
    float* n_out = (float*)d_out + (size_t)NG * H;       // [N,H]
    float* agg   = (float*)d_ws;                         // [G,H] scratch

    // agg := 0 (d_ws is poisoned 0xAA before every call)
    hipMemsetAsync(agg, 0, (size_t)NG * H * sizeof(float), stream);

    seg_sum_atomic<<<NN / SS_ROWS, 128, 0, stream>>>(updated_node, segment_ids, agg);

    // set MLP: rows = agg ++ updated_set (identity gather), cached stores
    mlp_mfma<1, false, false><<<NG / 16, 256, 0, stream>>>(
        agg, nullptr, updated_set, Ws1, bs1, Ws2, bs2, s_out);

    // node MLP: rows = node ++ s[seg], nontemporal stores
    mlp_mfma<8, true, true><<<NN / (8 * 16), 256, 0, stream>>>(
        updated_node, segment_ids, s_out, Wn1, bn1, Wn2, bn2, n_out);
}